// Round 2
// baseline (318.198 us; speedup 1.0000x reference)
//
#include <hip/hip_runtime.h>

// ---------------------------------------------------------------------------
// MultiHeadAttention fwd: out = softmax_causal((qWq^T+bq)(kWk^T+bk)^T/8)(vWv^T+bv) Wo^T + bo
// B=2 S=2048 D=1024 H=16 DK=64.  All GEMM-shaped compute in f16 MFMA, fp32 accum.
// ---------------------------------------------------------------------------

typedef _Float16 f16;
typedef __attribute__((ext_vector_type(4))) float   f32x4;
typedef __attribute__((ext_vector_type(8))) _Float16 f16x8;

#define DEVI __device__ __forceinline__

static constexpr int S  = 2048;
static constexpr int D  = 1024;
static constexpr int KK = 1024;           // GEMM inner dim
static constexpr int M  = 4096;           // B*S

DEVI void gload_lds16(const void* g, void* l) {
  __builtin_amdgcn_global_load_lds((const __attribute__((address_space(1))) void*)g,
                                   (__attribute__((address_space(3))) void*)l, 16, 0, 0);
}

DEVI f32x4 mfma16(f16x8 a, f16x8 b, f32x4 c) {
  return __builtin_amdgcn_mfma_f32_16x16x32_f16(a, b, c, 0, 0, 0);
}

// XOR swizzle for 128-byte LDS rows: spreads 16B chunks across banks.
DEVI int xorv(int row) { return ((row ^ (row >> 3)) & 7) << 4; }

// ---------------------------------------------------------------------------
// fp32 -> f16 conversion, 8 elems/thread. blockIdx.y selects source array.
// ---------------------------------------------------------------------------
__global__ __launch_bounds__(256) void cvt_kernel(const float* __restrict__ s0,
                                                  const float* __restrict__ s1,
                                                  const float* __restrict__ s2,
                                                  const float* __restrict__ s3,
                                                  f16* __restrict__ dst, int nper) {
  const float* s = blockIdx.y == 0 ? s0 : blockIdx.y == 1 ? s1 : blockIdx.y == 2 ? s2 : s3;
  f16* d = dst + (size_t)blockIdx.y * nper;
  const int i = (blockIdx.x * 256 + threadIdx.x) * 8;
  f32x4 a = *(const f32x4*)(s + i);
  f32x4 b = *(const f32x4*)(s + i + 4);
  f16x8 r;
#pragma unroll
  for (int j = 0; j < 4; ++j) { r[j] = (f16)a[j]; r[4 + j] = (f16)b[j]; }
  *(f16x8*)(d + i) = r;
}

// ---------------------------------------------------------------------------
// GEMM mainloop (m97 structure): C[128,128] tile, A[M,K] row-major,
// W[N,K] row-major (i.e. x @ W^T), BK=32, 4 waves each 64x64.
// ---------------------------------------------------------------------------
DEVI void gemm_mainloop(const f16* __restrict__ A, const f16* __restrict__ W,
                        int m0, int n0, f16* As, f16* Bs, f32x4 acc[4][4]) {
  const int tid  = threadIdx.x;
  const int wid  = tid >> 6;
  const int lane = tid & 63;
  const int wr = wid >> 1, wc = wid & 1;

  const f32x4 z4 = {0.f, 0.f, 0.f, 0.f};
#pragma unroll
  for (int mi = 0; mi < 4; ++mi)
#pragma unroll
    for (int ni = 0; ni < 4; ++ni) acc[mi][ni] = z4;

  // staging geometry: 512 slots of 16B per 8KB tile; slot -> row=slot>>2, col=(slot&3)*8
  const int r0 = tid >> 2, c0 = (tid & 3) * 8;
  const int r1 = 64 + r0;
  const f16* Ag0 = A + (size_t)(m0 + r0) * KK + c0;
  const f16* Ag1 = A + (size_t)(m0 + r1) * KK + c0;
  const f16* Bg0 = W + (size_t)(n0 + r0) * KK + c0;
  const f16* Bg1 = W + (size_t)(n0 + r1) * KK + c0;
  f16* As0 = As + wid * 512;        // wave-uniform LDS dest (lane*16B implicit)
  f16* As1 = As + 2048 + wid * 512;
  f16* Bs0 = Bs + wid * 512;
  f16* Bs1 = Bs + 2048 + wid * 512;

  const int arow = wr * 64 + (lane & 15);
  const int brow = wc * 64 + (lane & 15);
  const int ko   = (lane >> 4) * 8;

  for (int k0 = 0; k0 < KK; k0 += 32) {
    gload_lds16(Ag0 + k0, As0);
    gload_lds16(Ag1 + k0, As1);
    gload_lds16(Bg0 + k0, Bs0);
    gload_lds16(Bg1 + k0, Bs1);
    __syncthreads();
    f16x8 af[4], bf[4];
#pragma unroll
    for (int mi = 0; mi < 4; ++mi) af[mi] = *(const f16x8*)&As[(arow + mi * 16) * 32 + ko];
#pragma unroll
    for (int ni = 0; ni < 4; ++ni) bf[ni] = *(const f16x8*)&Bs[(brow + ni * 16) * 32 + ko];
#pragma unroll
    for (int mi = 0; mi < 4; ++mi)
#pragma unroll
      for (int ni = 0; ni < 4; ++ni)
        acc[mi][ni] = mfma16(af[mi], bf[ni], acc[mi][ni]);
    __syncthreads();
  }
}

// QKV projection: z selects (X, W, bias, dst). Writes head layout [bh][s][64].
// z==0 (Q) additionally multiplies by 1/sqrt(DK)=0.125.
__global__ __launch_bounds__(256, 2) void gemm_qkv_kernel(const f16* __restrict__ X,
                                                          const f16* __restrict__ Wp,
                                                          const float* __restrict__ b0,
                                                          const float* __restrict__ b1,
                                                          const float* __restrict__ b2,
                                                          f16* __restrict__ Hd) {
  __shared__ f16 As[128 * 32];
  __shared__ f16 Bs[128 * 32];
  const int z = blockIdx.z;
  const f16* A = X + (size_t)z * (M * KK);
  const f16* W = Wp + (size_t)z * (D * KK);
  const float* bias = z == 0 ? b0 : z == 1 ? b1 : b2;
  f16* dst = Hd + (size_t)z * (size_t)4194304;
  const float scale = (z == 0) ? 0.125f : 1.0f;
  const int m0 = blockIdx.y * 128, n0 = blockIdx.x * 128;

  f32x4 acc[4][4];
  gemm_mainloop(A, W, m0, n0, As, Bs, acc);

  const int lane = threadIdx.x & 63, wid = threadIdx.x >> 6;
  const int wr = wid >> 1, wc = wid & 1;
#pragma unroll
  for (int ni = 0; ni < 4; ++ni) {
    const int col = n0 + wc * 64 + ni * 16 + (lane & 15);
    const float bv = bias[col];
    const int h = col >> 6, dk = col & 63;
#pragma unroll
    for (int mi = 0; mi < 4; ++mi) {
#pragma unroll
      for (int r = 0; r < 4; ++r) {
        const int row = m0 + wr * 64 + mi * 16 + (lane >> 4) * 4 + r;
        const int bb = row >> 11, ss = row & 2047;
        dst[(size_t)((bb * 16 + h) * 2048 + ss) * 64 + dk] = (f16)((acc[mi][ni][r] + bv) * scale);
      }
    }
  }
}

// Output projection: plain [M,1024] fp32 output.
__global__ __launch_bounds__(256, 2) void gemm_out_kernel(const f16* __restrict__ A,
                                                          const f16* __restrict__ W,
                                                          const float* __restrict__ bias,
                                                          float* __restrict__ out) {
  __shared__ f16 As[128 * 32];
  __shared__ f16 Bs[128 * 32];
  const int m0 = blockIdx.y * 128, n0 = blockIdx.x * 128;
  f32x4 acc[4][4];
  gemm_mainloop(A, W, m0, n0, As, Bs, acc);
  const int lane = threadIdx.x & 63, wid = threadIdx.x >> 6;
  const int wr = wid >> 1, wc = wid & 1;
#pragma unroll
  for (int ni = 0; ni < 4; ++ni) {
    const int col = n0 + wc * 64 + ni * 16 + (lane & 15);
    const float bv = bias[col];
#pragma unroll
    for (int mi = 0; mi < 4; ++mi) {
#pragma unroll
      for (int r = 0; r < 4; ++r) {
        const int row = m0 + wr * 64 + mi * 16 + (lane >> 4) * 4 + r;
        out[(size_t)row * 1024 + col] = acc[mi][ni][r] + bv;
      }
    }
  }
}

// ---------------------------------------------------------------------------
// Flash attention, causal. Block = (128 q-rows, one bh). 4 waves x 32 rows.
// KVBLK=64. Q pre-scaled by 1/8 in projection. Layouts [bh][s][64] f16.
// Output written to [b][s][1024] f16 for the final projection.
// ---------------------------------------------------------------------------
__global__ __launch_bounds__(256, 2) void attn_kernel(const f16* __restrict__ Qh,
                                                      const f16* __restrict__ Kh,
                                                      const f16* __restrict__ Vh,
                                                      f16* __restrict__ Ao) {
  __shared__ f16 Ks[64 * 64];      // rows = kv, 128B rows, XOR-swizzled content
  __shared__ f16 Vt[64 * 64];      // rows = dk, cols = kv, XOR-swizzled
  __shared__ f16 Ps[4][32 * 64];   // per-wave P tile, rows = q-local, swizzled

  const int tid = threadIdx.x, wid = tid >> 6, lane = tid & 63;
  const int bh = blockIdx.y;
  const int q0 = blockIdx.x * 128;
  const int qw = q0 + wid * 32;                 // this wave's q base (seq index)
  const size_t base = (size_t)bh * (S * 64);

  // Q fragments: aq[mi][ks] ; A-operand layout row=lane&15, k=(lane>>4)*8
  f16x8 aq[2][2];
#pragma unroll
  for (int mi = 0; mi < 2; ++mi)
#pragma unroll
    for (int ks = 0; ks < 2; ++ks)
      aq[mi][ks] = *(const f16x8*)&Qh[base + (size_t)(qw + mi * 16 + (lane & 15)) * 64 +
                                      ks * 32 + (lane >> 4) * 8];

  const f32x4 z4 = {0.f, 0.f, 0.f, 0.f};
  f32x4 o[2][4];
  float mrow[2][4], lrow[2][4];
#pragma unroll
  for (int mi = 0; mi < 2; ++mi)
#pragma unroll
    for (int r = 0; r < 4; ++r) { mrow[mi][r] = -1e30f; lrow[mi][r] = 0.f; }
#pragma unroll
  for (int mi = 0; mi < 2; ++mi)
#pragma unroll
    for (int dj = 0; dj < 4; ++dj) o[mi][dj] = z4;

  const int ntiles = q0 / 64 + 2;               // kv tiles up to q0+128
  for (int t = 0; t < ntiles; ++t) {
    const int kv0 = t * 64;
    __syncthreads();   // previous tile's LDS reads finished before restaging

    // stage K tile via global_load_lds; source pre-swizzled so swizzled reads work
#pragma unroll
    for (int i = 0; i < 2; ++i) {
      const int sl = i * 256 + tid;
      const int row = sl >> 3;
      const int cb = (sl & 7) * 16;
      const int col = (cb ^ xorv(row)) >> 1;
      gload_lds16(Kh + base + (size_t)(kv0 + row) * 64 + col,
                  (char*)Ks + i * 4096 + wid * 1024);
    }
    // stage V transposed (reg->LDS scatter, swizzled)
#pragma unroll
    for (int r2 = 0; r2 < 2; ++r2) {
      const int kv = r2 * 32 + (tid >> 3);
      const int dk0 = (tid & 7) * 8;
      f16x8 vv = *(const f16x8*)&Vh[base + (size_t)(kv0 + kv) * 64 + dk0];
#pragma unroll
      for (int j = 0; j < 8; ++j) {
        const int dk = dk0 + j;
        *(f16*)((char*)Vt + dk * 128 + ((kv * 2) ^ xorv(dk))) = vv[j];
      }
    }
    __syncthreads();

    if (kv0 <= qw + 31) {                       // wave has visible keys in this tile
      // ---- QK^T ----
      f32x4 sc[2][4];
#pragma unroll
      for (int mi = 0; mi < 2; ++mi)
#pragma unroll
        for (int nj = 0; nj < 4; ++nj) sc[mi][nj] = z4;
#pragma unroll
      for (int nj = 0; nj < 4; ++nj) {
        const int krow = nj * 16 + (lane & 15);
#pragma unroll
        for (int ks = 0; ks < 2; ++ks) {
          f16x8 bk = *(const f16x8*)((char*)Ks + krow * 128 +
                                     ((ks * 64 + (lane >> 4) * 16) ^ xorv(krow)));
          sc[0][nj] = mfma16(aq[0][ks], bk, sc[0][nj]);
          sc[1][nj] = mfma16(aq[1][ks], bk, sc[1][nj]);
        }
      }
      // ---- causal mask ----
      if (kv0 + 63 > qw) {
#pragma unroll
        for (int mi = 0; mi < 2; ++mi)
#pragma unroll
          for (int nj = 0; nj < 4; ++nj)
#pragma unroll
            for (int r = 0; r < 4; ++r) {
              const int qq = qw + mi * 16 + (lane >> 4) * 4 + r;
              const int kv = kv0 + nj * 16 + (lane & 15);
              if (kv > qq) sc[mi][nj][r] = -1e30f;
            }
      }
      // ---- online softmax ----
      float mnew[2][4], scl[2][4], psum[2][4];
#pragma unroll
      for (int mi = 0; mi < 2; ++mi)
#pragma unroll
        for (int r = 0; r < 4; ++r) {
          float mx = fmaxf(fmaxf(sc[mi][0][r], sc[mi][1][r]), fmaxf(sc[mi][2][r], sc[mi][3][r]));
#pragma unroll
          for (int off = 1; off < 16; off <<= 1) mx = fmaxf(mx, __shfl_xor(mx, off));
          const float mn = fmaxf(mrow[mi][r], mx);
          mnew[mi][r] = mn;
          scl[mi][r]  = exp2f((mrow[mi][r] - mn) * 1.44269504f);
          psum[mi][r] = 0.f;
        }
#pragma unroll
      for (int mi = 0; mi < 2; ++mi)
#pragma unroll
        for (int nj = 0; nj < 4; ++nj) {
#pragma unroll
          for (int r = 0; r < 4; ++r) {
            const float p = exp2f((sc[mi][nj][r] - mnew[mi][r]) * 1.44269504f);
            psum[mi][r] += p;
            const int ql = mi * 16 + (lane >> 4) * 4 + r;
            const int kvl = nj * 16 + (lane & 15);
            *(f16*)((char*)Ps[wid] + ql * 128 + ((kvl * 2) ^ xorv(ql))) = (f16)p;
          }
        }
#pragma unroll
      for (int mi = 0; mi < 2; ++mi)
#pragma unroll
        for (int r = 0; r < 4; ++r) {
          float ps = psum[mi][r];
#pragma unroll
          for (int off = 1; off < 16; off <<= 1) ps += __shfl_xor(ps, off);
          lrow[mi][r] = lrow[mi][r] * scl[mi][r] + ps;
          mrow[mi][r] = mnew[mi][r];
        }
      // ---- rescale O ----
#pragma unroll
      for (int mi = 0; mi < 2; ++mi)
#pragma unroll
        for (int dj = 0; dj < 4; ++dj)
#pragma unroll
          for (int r = 0; r < 4; ++r) o[mi][dj][r] *= scl[mi][r];
      // ---- PV ----  (Ps writes above are same-wave; DS ops are in-order)
#pragma unroll
      for (int ks = 0; ks < 2; ++ks) {
        f16x8 pa[2];
#pragma unroll
        for (int mi = 0; mi < 2; ++mi) {
          const int ql = mi * 16 + (lane & 15);
          pa[mi] = *(const f16x8*)((char*)Ps[wid] + ql * 128 +
                                   ((ks * 64 + (lane >> 4) * 16) ^ xorv(ql)));
        }
#pragma unroll
        for (int dj = 0; dj < 4; ++dj) {
          const int dr = dj * 16 + (lane & 15);
          f16x8 bv = *(const f16x8*)((char*)Vt + dr * 128 +
                                     ((ks * 64 + (lane >> 4) * 16) ^ xorv(dr)));
          o[0][dj] = mfma16(pa[0], bv, o[0][dj]);
          o[1][dj] = mfma16(pa[1], bv, o[1][dj]);
        }
      }
    }
  }

  // epilogue: O /= l, write [b][s][1024] f16
  const int bb = bh >> 4, hh = bh & 15;
#pragma unroll
  for (int mi = 0; mi < 2; ++mi)
#pragma unroll
    for (int r = 0; r < 4; ++r) {
      const float inv = 1.0f / lrow[mi][r];
      const int qq = qw + mi * 16 + (lane >> 4) * 4 + r;
#pragma unroll
      for (int dj = 0; dj < 4; ++dj) {
        const int dk = dj * 16 + (lane & 15);
        Ao[(size_t)(bb * 2048 + qq) * 1024 + hh * 64 + dk] = (f16)(o[mi][dj][r] * inv);
      }
    }
}

// ---------------------------------------------------------------------------
extern "C" void kernel_launch(void* const* d_in, const int* in_sizes, int n_in,
                              void* d_out, int out_size, void* d_ws, size_t ws_size,
                              hipStream_t stream) {
  const float* q  = (const float*)d_in[0];
  const float* k  = (const float*)d_in[1];
  const float* v  = (const float*)d_in[2];
  // d_in[3] = causal mask (tril), implemented structurally
  const float* Wq = (const float*)d_in[4];  const float* bq = (const float*)d_in[5];
  const float* Wk = (const float*)d_in[6];  const float* bk = (const float*)d_in[7];
  const float* Wv = (const float*)d_in[8];  const float* bv = (const float*)d_in[9];
  const float* Wo = (const float*)d_in[10]; const float* bo = (const float*)d_in[11];
  float* out = (float*)d_out;

  char* ws = (char*)d_ws;
  f16* xb = (f16*)(ws);                       // q,k,v f16: 3 * 4194304 elems
  f16* wb = (f16*)(ws + 25165824);            // Wq,Wk,Wv,Wo f16: 4 * 1048576
  f16* hb = (f16*)(ws + 33554432);            // Qh,Kh,Vh head layout: 3 * 4194304
  f16* ao = (f16*)(ws + 58720256);            // attention out [4096][1024]: 4194304
  // total 67108864 bytes (64 MiB)

  cvt_kernel<<<dim3(2048, 3), 256, 0, stream>>>(q, k, v, nullptr, xb, 4194304);
  cvt_kernel<<<dim3(512, 4), 256, 0, stream>>>(Wq, Wk, Wv, Wo, wb, 1048576);
  gemm_qkv_kernel<<<dim3(8, 32, 3), 256, 0, stream>>>(xb, wb, bq, bk, bv, hb);
  attn_kernel<<<dim3(16, 32), 256, 0, stream>>>(hb, hb + 4194304, hb + 8388608, ao);
  gemm_out_kernel<<<dim3(8, 32), 256, 0, stream>>>(ao, wb + 3 * 1048576, bo, out);
}